// Round 5
// baseline (175.291 us; speedup 1.0000x reference)
//
#include <hip/hip_runtime.h>
#include <stdint.h>

typedef float v2f __attribute__((ext_vector_type(2)));

// channel-gather lists for the 16 branch convs
constexpr int IDX3[18] = {0,1,2, 1,2,3, 2,3,4, 3,4,5, 0,4,5, 0,1,5};
constexpr int IDX4[36] = {0,1,2,3, 1,2,3,4, 2,3,4,5, 0,3,4,5, 0,1,4,5,
                          0,1,2,5, 0,1,3,4, 1,2,4,5, 0,2,3,5};

// ws layout (uint32 units):
//   [0..18)     w3 25-bit masks (br*3+j)
//   [18..54)    w4 25-bit masks (br*4+j)
//   [54..60)    w6 25-bit masks (c)
//   [60..1620)  c5 masks, 13 u32 per oc; bit g=w*32+b -> qi=g>>4, ic=g&15

__global__ void prepack_kernel(const float* __restrict__ w3, const float* __restrict__ w4,
                               const float* __restrict__ w6, const float* __restrict__ c5w,
                               unsigned* __restrict__ ws) {
    int t = blockIdx.x * blockDim.x + threadIdx.x;
    if (t < 60) {
        const float* src = (t < 18) ? (w3 + t * 25)
                          : (t < 54) ? (w4 + (t - 18) * 25)
                          : (w6 + (t - 54) * 25);
        unsigned m = 0;
        for (int p = 0; p < 25; ++p) if (src[p] > 0.f) m |= 1u << p;
        ws[t] = m;
    } else if (t < 1620) {
        int q = t - 60, oc = q / 13, w = q % 13;
        unsigned m = 0;
        for (int b = 0; b < 32; ++b) {
            int g = w * 32 + b;           // bit position = qi*16 + ic
            int qi = g >> 4, ic = g & 15;
            if (qi < 25 && c5w[oc * 400 + ic * 25 + qi] > 0.f) m |= 1u << b;
        }
        ws[60 + q] = m;
    }
}

// padded image tile: row stride 36 floats, img stride 1156 floats
#define ROWS 36
#define IMGS 1156

__device__ __forceinline__ void c5_eval(const unsigned cw[13], int tot,
                                        const unsigned* __restrict__ ws,
                                        const float* __restrict__ c5b,
                                        int lane, unsigned h5w[4]) {
    // round A: oc = lane (0..63)
    {
        const unsigned* cm = ws + 60 + lane * 13;
        int sum = 0;
        #pragma unroll
        for (int w = 0; w < 13; ++w) sum += __popc(cw[w] & cm[w]);
        bool pred = ((float)(2 * sum - tot) + c5b[lane]) > 0.f;
        unsigned long long m = __ballot(pred);
        h5w[0] = (unsigned)m;
        h5w[1] = (unsigned)(m >> 32);
    }
    // round B: oc = 64 + lane (64..119)
    {
        int oc = 64 + lane;
        bool pred = false;
        if (oc < 120) {
            const unsigned* cm = ws + 60 + oc * 13;
            int sum = 0;
            #pragma unroll
            for (int w = 0; w < 13; ++w) sum += __popc(cw[w] & cm[w]);
            pred = ((float)(2 * sum - tot) + c5b[oc]) > 0.f;
        }
        unsigned long long m = __ballot(pred);
        h5w[2] = (unsigned)m;
        h5w[3] = (unsigned)(m >> 32);
    }
}

// One wave (64 threads) per block, 2 images per block. All barriers are
// single-wave (no cross-wave coupling); phase tasks map onto 64 lanes.
__global__ __launch_bounds__(64) void lenet_fused(
    const float* __restrict__ x, const float* __restrict__ c1w, const float* __restrict__ c1b,
    const float* __restrict__ b3, const float* __restrict__ b4, const float* __restrict__ b6,
    const float* __restrict__ c5b, const unsigned* __restrict__ ws,
    const float* __restrict__ f6w, const float* __restrict__ f6b,
    const float* __restrict__ rbfw, const float* __restrict__ rbfb,
    float* __restrict__ out, int B) {
    __shared__ float xs[2 * IMGS];
    __shared__ float wS[150];
    __shared__ float bS[6], b3S[6], b4S[9], b6S[1];
    __shared__ unsigned hrow[2][6][14];   // 14-bit pooled-sign rows of stage 1
    __shared__ unsigned sbits[2][100];    // per-pixel 16-bit branch sign masks
    __shared__ unsigned c5in[2][13];      // 400-bit c5 input, bit = qi*16+ic
    __shared__ float f6o[2][84];

    const int t = threadIdx.x;            // lane 0..63
    const int img0 = blockIdx.x * 2;
    const int nimg = min(2, B - img0);

    // ---- phase 0: stage x into padded LDS tile + small tables ----
    {
        const float4* src = (const float4*)(x + (size_t)img0 * 1024);
        for (int i = t; i < nimg * 256; i += 64) {
            int img = i >> 8, r = (i >> 3) & 31, q = i & 7;
            ((float4*)xs)[img * 289 + r * 9 + q] = src[i];
        }
    }
    for (int i = t; i < 150; i += 64) wS[i] = c1w[i];
    if (t < 6) { bS[t] = c1b[t]; b3S[t] = b3[t]; }
    if (t < 9) b4S[t] = b4[t];
    if (t == 0) b6S[0] = b6[0];
    __syncthreads();

    // ---- phase 1: c1 conv + relu + pool + sign ----
    // 168 tasks (img,c,py) over 64 lanes. Two output rows packed as v2f
    // accumulators -> v_pk_fma_f32 via fp contraction; weight pairs premade.
    for (int q = t; q < 2 * 84; q += 64) {
        int py = q / 12, rem = q % 12, img = rem / 6, c = rem % 6;
        const float* wc = wS + c * 25;
        float w0[5], w4r[5];
        v2f wp[20];
        #pragma unroll
        for (int kw = 0; kw < 5; ++kw) { w0[kw] = wc[kw]; w4r[kw] = wc[20 + kw]; }
        #pragma unroll
        for (int r = 1; r <= 4; ++r)
            #pragma unroll
            for (int kw = 0; kw < 5; ++kw)
                wp[(r - 1) * 5 + kw] = (v2f){wc[r * 5 + kw], wc[(r - 1) * 5 + kw]};
        const float bias = bS[c];
        const float* xp = xs + img * IMGS + (2 * py) * ROWS;
        unsigned m = 0;
        #pragma unroll 1
        for (int ch = 0; ch < 7; ++ch) {
            v2f accp[4];
            #pragma unroll
            for (int j = 0; j < 4; ++j) accp[j] = (v2f){bias, bias};
            #pragma unroll
            for (int r = 0; r < 6; ++r) {
                const float4* rp = (const float4*)(xp + r * ROWS + 4 * ch);
                float4 va = rp[0];
                float4 vb = rp[1];
                float win[8] = {va.x, va.y, va.z, va.w, vb.x, vb.y, vb.z, vb.w};
                if (r == 0) {
                    #pragma unroll
                    for (int kw = 0; kw < 5; ++kw)
                        #pragma unroll
                        for (int j = 0; j < 4; ++j)
                            accp[j].x = fmaf(win[j + kw], w0[kw], accp[j].x);
                } else if (r == 5) {
                    #pragma unroll
                    for (int kw = 0; kw < 5; ++kw)
                        #pragma unroll
                        for (int j = 0; j < 4; ++j)
                            accp[j].y = fmaf(win[j + kw], w4r[kw], accp[j].y);
                } else {
                    #pragma unroll
                    for (int kw = 0; kw < 5; ++kw) {
                        v2f w2 = wp[(r - 1) * 5 + kw];
                        #pragma unroll
                        for (int j = 0; j < 4; ++j) {
                            v2f x2 = (v2f){win[j + kw], win[j + kw]};
                            accp[j] = x2 * w2 + accp[j];   // contracts to v_pk_fma_f32
                        }
                    }
                }
            }
            float m0 = fmaxf(fmaxf(accp[0].x, accp[0].y), fmaxf(accp[1].x, accp[1].y));
            float m1 = fmaxf(fmaxf(accp[2].x, accp[2].y), fmaxf(accp[3].x, accp[3].y));
            unsigned bits = (m0 > 0.f ? 1u : 0u) | (m1 > 0.f ? 2u : 0u);
            m |= bits << (2 * ch);   // avgpool(relu)>0 <=> any conv>0
        }
        hrow[img][c][py] = m;
    }
    __syncthreads();

    // ---- phase 2: 16 binary branch convs per 10x10 pixel, 25-bit packed popcounts ----
    for (int q = t; q < 2 * 100; q += 64) {
        int img = (q >= 100) ? 1 : 0, p = q - img * 100, oy = p / 10, ox = p % 10;
        unsigned win[6];
        int wpop[6];
        #pragma unroll
        for (int c = 0; c < 6; ++c) {
            unsigned w = 0;
            #pragma unroll
            for (int r = 0; r < 5; ++r)
                w |= ((hrow[img][c][oy + r] >> ox) & 31u) << (5 * r);
            win[c] = w;
            wpop[c] = __popc(w);
        }
        unsigned m16 = 0;
        #pragma unroll
        for (int br = 0; br < 6; ++br) {
            int sum = 0, tot = 0;
            #pragma unroll
            for (int j = 0; j < 3; ++j) {
                int c = IDX3[br * 3 + j];
                tot += wpop[c];
                sum += __popc(win[c] & ws[br * 3 + j]);
            }
            if ((float)(2 * sum - tot) + b3S[br] > 0.f) m16 |= 1u << br;
        }
        #pragma unroll
        for (int br = 0; br < 9; ++br) {
            int sum = 0, tot = 0;
            #pragma unroll
            for (int j = 0; j < 4; ++j) {
                int c = IDX4[br * 4 + j];
                tot += wpop[c];
                sum += __popc(win[c] & ws[18 + br * 4 + j]);
            }
            if ((float)(2 * sum - tot) + b4S[br] > 0.f) m16 |= 1u << (6 + br);
        }
        {
            int sum = 0, tot = 0;
            #pragma unroll
            for (int c = 0; c < 6; ++c) {
                tot += wpop[c];
                sum += __popc(win[c] & ws[54 + c]);
            }
            if ((float)(2 * sum - tot) + b6S[0] > 0.f) m16 |= 1u << 15;
        }
        sbits[img][p] = m16;
    }
    __syncthreads();

    // ---- phase 2b: relu+pool+sign -> 400-bit c5 input, word-at-a-time ----
    if (t < 2 * 13) {
        int img = (t >= 13) ? 1 : 0, j = t - img * 13;
        int qi0 = 2 * j;
        int qy = qi0 / 5, qx = qi0 % 5, base = 2 * qy * 10 + 2 * qx;
        unsigned a0 = sbits[img][base] | sbits[img][base + 1] |
                      sbits[img][base + 10] | sbits[img][base + 11];
        unsigned word = a0 & 0xFFFFu;
        if (j < 12) {
            int qi1 = qi0 + 1;
            qy = qi1 / 5; qx = qi1 % 5; base = 2 * qy * 10 + 2 * qx;
            unsigned a1 = sbits[img][base] | sbits[img][base + 1] |
                          sbits[img][base + 10] | sbits[img][base + 11];
            word |= (a1 & 0xFFFFu) << 16;
        }
        c5in[img][j] = word;
    }
    __syncthreads();

    // ---- phase 3: c5 binary conv -> 120 sign bits per image, via __ballot ----
    unsigned h50[4], h51[4];
    {
        unsigned cw[13];
        int tot = 0;
        #pragma unroll
        for (int w = 0; w < 13; ++w) { cw[w] = c5in[0][w]; tot += __popc(cw[w]); }
        c5_eval(cw, tot, ws, c5b, t, h50);
    }
    {
        unsigned cw[13];
        int tot = 0;
        #pragma unroll
        for (int w = 0; w < 13; ++w) { cw[w] = c5in[1][w]; tot += __popc(cw[w]); }
        c5_eval(cw, tot, ws, c5b, t, h51);
    }

    // ---- phase 4: f6 (+-1 dot, 120 wide) + tanh; f6w row shared by both images ----
    #pragma unroll 1
    for (int jr = 0; jr < 2; ++jr) {
        int j = jr * 64 + t;
        if (j < 84) {
            float a0 = f6b[j], a1 = a0;
            const float4* wrow = (const float4*)f6w + j * 30;
            #pragma unroll 5
            for (int kk = 0; kk < 30; ++kk) {
                float4 wv = wrow[kk];
                float we[4] = {wv.x, wv.y, wv.z, wv.w};
                #pragma unroll
                for (int e = 0; e < 4; ++e) {
                    int k = 4 * kk + e;
                    float w = we[e];
                    a0 += ((h50[k >> 5] >> (k & 31)) & 1u) ? w : -w;
                    a1 += ((h51[k >> 5] >> (k & 31)) & 1u) ? w : -w;
                }
            }
            f6o[0][j] = tanhf(1.7519f * a0);
            f6o[1][j] = tanhf(1.7519f * a1);
        }
    }
    __syncthreads();

    // ---- phase 5: rbf + relu -> out ----
    if (t < nimg * 10) {
        int img = (t >= 10) ? 1 : 0, oc = t - img * 10;
        float sum = rbfb[oc];
        const float4* rw = (const float4*)(rbfw + oc * 84);
        #pragma unroll
        for (int kk = 0; kk < 21; ++kk) {
            float4 wv = rw[kk];
            int j = 4 * kk;
            sum = fmaf(f6o[img][j + 0], wv.x, sum);
            sum = fmaf(f6o[img][j + 1], wv.y, sum);
            sum = fmaf(f6o[img][j + 2], wv.z, sum);
            sum = fmaf(f6o[img][j + 3], wv.w, sum);
        }
        out[(size_t)(img0 + img) * 10 + oc] = fmaxf(sum, 0.f);
    }
}

extern "C" void kernel_launch(void* const* d_in, const int* in_sizes, int n_in,
                              void* d_out, int out_size, void* d_ws, size_t ws_size,
                              hipStream_t stream) {
    const float* x    = (const float*)d_in[0];
    const float* c1w  = (const float*)d_in[1];
    const float* c1b  = (const float*)d_in[2];
    const float* w3   = (const float*)d_in[3];
    const float* b3   = (const float*)d_in[4];
    const float* w4   = (const float*)d_in[5];
    const float* b4   = (const float*)d_in[6];
    const float* w6   = (const float*)d_in[7];
    const float* b6   = (const float*)d_in[8];
    const float* c5w  = (const float*)d_in[9];
    const float* c5b  = (const float*)d_in[10];
    const float* f6w  = (const float*)d_in[11];
    const float* f6b  = (const float*)d_in[12];
    const float* rbfw = (const float*)d_in[13];
    const float* rbfb = (const float*)d_in[14];
    const int B = in_sizes[0] / 1024;

    unsigned* ws = (unsigned*)d_ws;

    prepack_kernel<<<dim3(7), dim3(256), 0, stream>>>(w3, w4, w6, c5w, ws);
    lenet_fused<<<dim3((B + 1) / 2), dim3(64), 0, stream>>>(
        x, c1w, c1b, b3, b4, b6, c5b, ws, f6w, f6b, rbfw, rbfb, (float*)d_out, B);
}

// Round 6
// 150.113 us; speedup vs baseline: 1.1677x; 1.1677x over previous
//
#include <hip/hip_runtime.h>
#include <stdint.h>

typedef float v2f __attribute__((ext_vector_type(2)));

// channel-gather lists for the 16 branch convs
constexpr int IDX3[18] = {0,1,2, 1,2,3, 2,3,4, 3,4,5, 0,4,5, 0,1,5};
constexpr int IDX4[36] = {0,1,2,3, 1,2,3,4, 2,3,4,5, 0,3,4,5, 0,1,4,5,
                          0,1,2,5, 0,1,3,4, 1,2,4,5, 0,2,3,5};

// ws layout (uint32 units):
//   [0..18)     w3 25-bit masks (br*3+j)
//   [18..54)    w4 25-bit masks (br*4+j)
//   [54..60)    w6 25-bit masks (c)
//   [60..1620)  c5 masks, 13 u32 per oc; bit g=w*32+b -> qi=g>>4, ic=g&15

__global__ void prepack_kernel(const float* __restrict__ w3, const float* __restrict__ w4,
                               const float* __restrict__ w6, const float* __restrict__ c5w,
                               unsigned* __restrict__ ws) {
    int t = blockIdx.x * blockDim.x + threadIdx.x;
    if (t < 60) {
        const float* src = (t < 18) ? (w3 + t * 25)
                          : (t < 54) ? (w4 + (t - 18) * 25)
                          : (w6 + (t - 54) * 25);
        unsigned m = 0;
        for (int p = 0; p < 25; ++p) if (src[p] > 0.f) m |= 1u << p;
        ws[t] = m;
    } else if (t < 1620) {
        int q = t - 60, oc = q / 13, w = q % 13;
        unsigned m = 0;
        for (int b = 0; b < 32; ++b) {
            int g = w * 32 + b;           // bit position = qi*16 + ic
            int qi = g >> 4, ic = g & 15;
            if (qi < 25 && c5w[oc * 400 + ic * 25 + qi] > 0.f) m |= 1u << b;
        }
        ws[60 + q] = m;
    }
}

// padded image tile: row stride 36 floats (bank +4/row), img stride 1156 (bank +4/img)
#define ROWS 36
#define IMGS 1156

__global__ __launch_bounds__(256, 4) void lenet_fused(
    const float* __restrict__ x, const float* __restrict__ c1w, const float* __restrict__ c1b,
    const float* __restrict__ b3, const float* __restrict__ b4, const float* __restrict__ b6,
    const float* __restrict__ c5b, const unsigned* __restrict__ ws,
    const float* __restrict__ f6w, const float* __restrict__ f6b,
    const float* __restrict__ rbfw, const float* __restrict__ rbfb,
    float* __restrict__ out, int B) {
    __shared__ float xs[3 * IMGS];
    __shared__ float wS[150];
    __shared__ float bS[6], b3S[6], b4S[9], b6S[1];
    __shared__ unsigned hrow[3][6][14];   // 14-bit pooled-sign rows of stage 1
    __shared__ unsigned sbits[3][100];    // per-pixel 16-bit branch sign masks
    __shared__ unsigned c5in[3][13];      // 400-bit c5 input, bit = qi*16+ic
    __shared__ float4 sS4[3][30];         // c5 output as +-1 floats (120 per img)
    __shared__ float f6o[3][84];

    const int t = threadIdx.x;
    const int img0 = blockIdx.x * 3;
    const int nimg = min(3, B - img0);

    // ---- phase 0: stage x into padded LDS tile ----
    {
        const float4* src = (const float4*)(x + (size_t)img0 * 1024);
        for (int i = t; i < nimg * 256; i += 256) {
            int img = i >> 8, r = (i >> 3) & 31, q = i & 7;
            ((float4*)xs)[img * 289 + r * 9 + q] = src[i];
        }
    }
    if (t < 150) wS[t] = c1w[t];
    if (t < 6) { bS[t] = c1b[t]; b3S[t] = b3[t]; }
    if (t < 9) b4S[t] = b4[t];
    if (t == 0) b6S[0] = b6[0];
    __syncthreads();

    // ---- phase 1: c1 conv + relu + pool + sign ----
    // Full 28-wide row, both pooled output rows packed in a v2f accumulator ->
    // v_pk_fma_f32 via fp contraction on rows 1..4 (each input row feeds both
    // output rows). Rows 0 and 5 update one half scalar.
    // mapping t = py*(6*nimg)+img*6+c keeps xs reads <=2-way bank-aliased.
    if (t < nimg * 84) {
        const int denom = nimg * 6;
        int py = t / denom, rem = t % denom, img = rem / 6, c = rem % 6;
        float wr[25];
        #pragma unroll
        for (int i = 0; i < 25; ++i) wr[i] = wS[c * 25 + i];
        const float bias = bS[c];
        v2f accp[28];
        #pragma unroll
        for (int j = 0; j < 28; ++j) accp[j] = (v2f){bias, bias};
        const float* xp = xs + img * IMGS + (2 * py) * ROWS;
        #pragma unroll
        for (int r = 0; r < 6; ++r) {
            float rv[32];
            #pragma unroll
            for (int q = 0; q < 8; ++q) {
                float4 v = ((const float4*)(xp + r * ROWS))[q];
                rv[4 * q] = v.x; rv[4 * q + 1] = v.y; rv[4 * q + 2] = v.z; rv[4 * q + 3] = v.w;
            }
            if (r == 0) {
                #pragma unroll
                for (int kw = 0; kw < 5; ++kw) {
                    float wv = wr[kw];
                    #pragma unroll
                    for (int cx = 0; cx < 28; ++cx)
                        accp[cx].x = fmaf(rv[cx + kw], wv, accp[cx].x);
                }
            } else if (r == 5) {
                #pragma unroll
                for (int kw = 0; kw < 5; ++kw) {
                    float wv = wr[20 + kw];
                    #pragma unroll
                    for (int cx = 0; cx < 28; ++cx)
                        accp[cx].y = fmaf(rv[cx + kw], wv, accp[cx].y);
                }
            } else {
                v2f wp[5];
                #pragma unroll
                for (int kw = 0; kw < 5; ++kw)
                    wp[kw] = (v2f){wr[r * 5 + kw], wr[(r - 1) * 5 + kw]};
                #pragma unroll
                for (int kw = 0; kw < 5; ++kw) {
                    v2f w2 = wp[kw];
                    #pragma unroll
                    for (int cx = 0; cx < 28; ++cx) {
                        v2f x2 = (v2f){rv[cx + kw], rv[cx + kw]};
                        accp[cx] = x2 * w2 + accp[cx];   // contracts to v_pk_fma_f32
                    }
                }
            }
        }
        unsigned m = 0;
        #pragma unroll
        for (int px = 0; px < 14; ++px) {
            float mx = fmaxf(fmaxf(accp[2 * px].x, accp[2 * px].y),
                             fmaxf(accp[2 * px + 1].x, accp[2 * px + 1].y));
            if (mx > 0.f) m |= 1u << px;  // avgpool(relu)>0 <=> any conv>0
        }
        hrow[img][c][py] = m;
    }
    __syncthreads();

    // ---- phase 2: 16 binary branch convs per 10x10 pixel, 25-bit packed popcounts ----
    for (int q = t; q < nimg * 100; q += 256) {
        int img = q / 100, p = q % 100, oy = p / 10, ox = p % 10;
        unsigned win[6];
        int wpop[6];
        #pragma unroll
        for (int c = 0; c < 6; ++c) {
            unsigned w = 0;
            #pragma unroll
            for (int r = 0; r < 5; ++r)
                w |= ((hrow[img][c][oy + r] >> ox) & 31u) << (5 * r);
            win[c] = w;
            wpop[c] = __popc(w);
        }
        unsigned m16 = 0;
        #pragma unroll
        for (int br = 0; br < 6; ++br) {
            int sum = 0, tot = 0;
            #pragma unroll
            for (int j = 0; j < 3; ++j) {
                int c = IDX3[br * 3 + j];
                tot += wpop[c];
                sum += __popc(win[c] & ws[br * 3 + j]);
            }
            if ((float)(2 * sum - tot) + b3S[br] > 0.f) m16 |= 1u << br;
        }
        #pragma unroll
        for (int br = 0; br < 9; ++br) {
            int sum = 0, tot = 0;
            #pragma unroll
            for (int j = 0; j < 4; ++j) {
                int c = IDX4[br * 4 + j];
                tot += wpop[c];
                sum += __popc(win[c] & ws[18 + br * 4 + j]);
            }
            if ((float)(2 * sum - tot) + b4S[br] > 0.f) m16 |= 1u << (6 + br);
        }
        {
            int sum = 0, tot = 0;
            #pragma unroll
            for (int c = 0; c < 6; ++c) {
                tot += wpop[c];
                sum += __popc(win[c] & ws[54 + c]);
            }
            if ((float)(2 * sum - tot) + b6S[0] > 0.f) m16 |= 1u << 15;
        }
        sbits[img][p] = m16;
    }
    __syncthreads();

    // ---- phase 2b: relu+pool+sign -> 400-bit c5 input, word-at-a-time (no atomics) ----
    for (int q = t; q < nimg * 13; q += 256) {
        int img = q / 13, j = q % 13;
        int qi0 = 2 * j;
        int qy = qi0 / 5, qx = qi0 % 5, base = 2 * qy * 10 + 2 * qx;
        unsigned a0 = sbits[img][base] | sbits[img][base + 1] |
                      sbits[img][base + 10] | sbits[img][base + 11];
        unsigned word = a0 & 0xFFFFu;
        if (j < 12) {
            int qi1 = qi0 + 1;
            qy = qi1 / 5; qx = qi1 % 5; base = 2 * qy * 10 + 2 * qx;
            unsigned a1 = sbits[img][base] | sbits[img][base + 1] |
                          sbits[img][base + 10] | sbits[img][base + 11];
            word |= (a1 & 0xFFFFu) << 16;
        }
        c5in[img][j] = word;
    }
    __syncthreads();

    // ---- phase 3: c5 binary conv -> +-1 float vector in LDS (no ballot/atomics) ----
    for (int q = t; q < nimg * 120; q += 256) {
        int img = q / 120, oc = q % 120;
        const unsigned* cm = ws + 60 + oc * 13;
        int sum = 0, tot = 0;
        #pragma unroll
        for (int w = 0; w < 13; ++w) {
            unsigned inw = c5in[img][w];
            tot += __popc(inw);
            sum += __popc(inw & cm[w]);
        }
        bool pos = ((float)(2 * sum - tot) + c5b[oc]) > 0.f;
        ((float*)sS4)[img * 120 + oc] = pos ? 1.f : -1.f;
    }
    __syncthreads();

    // ---- phase 4: f6 = f6w @ s + b, tanh; plain FMA dot over broadcast LDS reads ----
    if (t < nimg * 84) {
        int img = t / 84, j = t % 84;
        float acc = f6b[j];
        const float4* wrow = (const float4*)f6w + j * 30;
        #pragma unroll 6
        for (int kk = 0; kk < 30; ++kk) {
            float4 wv = wrow[kk];
            float4 sv = sS4[img][kk];
            acc = fmaf(sv.x, wv.x, acc);
            acc = fmaf(sv.y, wv.y, acc);
            acc = fmaf(sv.z, wv.z, acc);
            acc = fmaf(sv.w, wv.w, acc);
        }
        f6o[img][j] = tanhf(1.7519f * acc);
    }
    __syncthreads();

    // ---- phase 5: rbf + relu -> out ----
    if (t < nimg * 10) {
        int img = t / 10, oc = t % 10;
        float sum = rbfb[oc];
        const float4* rw = (const float4*)(rbfw + oc * 84);
        #pragma unroll
        for (int kk = 0; kk < 21; ++kk) {
            float4 wv = rw[kk];
            int j = 4 * kk;
            sum = fmaf(f6o[img][j + 0], wv.x, sum);
            sum = fmaf(f6o[img][j + 1], wv.y, sum);
            sum = fmaf(f6o[img][j + 2], wv.z, sum);
            sum = fmaf(f6o[img][j + 3], wv.w, sum);
        }
        out[(size_t)(img0 + img) * 10 + oc] = fmaxf(sum, 0.f);
    }
}

extern "C" void kernel_launch(void* const* d_in, const int* in_sizes, int n_in,
                              void* d_out, int out_size, void* d_ws, size_t ws_size,
                              hipStream_t stream) {
    const float* x    = (const float*)d_in[0];
    const float* c1w  = (const float*)d_in[1];
    const float* c1b  = (const float*)d_in[2];
    const float* w3   = (const float*)d_in[3];
    const float* b3   = (const float*)d_in[4];
    const float* w4   = (const float*)d_in[5];
    const float* b4   = (const float*)d_in[6];
    const float* w6   = (const float*)d_in[7];
    const float* b6   = (const float*)d_in[8];
    const float* c5w  = (const float*)d_in[9];
    const float* c5b  = (const float*)d_in[10];
    const float* f6w  = (const float*)d_in[11];
    const float* f6b  = (const float*)d_in[12];
    const float* rbfw = (const float*)d_in[13];
    const float* rbfb = (const float*)d_in[14];
    const int B = in_sizes[0] / 1024;

    unsigned* ws = (unsigned*)d_ws;

    prepack_kernel<<<dim3(7), dim3(256), 0, stream>>>(w3, w4, w6, c5w, ws);
    lenet_fused<<<dim3((B + 2) / 3), dim3(256), 0, stream>>>(
        x, c1w, c1b, b3, b4, b6, c5b, ws, f6w, f6b, rbfw, rbfb, (float*)d_out, B);
}